// Round 1
// baseline (438.524 us; speedup 1.0000x reference)
//
#include <hip/hip_runtime.h>

#define PI_F 3.14159265358979323846f

typedef __attribute__((ext_vector_type(8))) short short8;
typedef __attribute__((ext_vector_type(4))) float floatx4;

__device__ __forceinline__ unsigned short f2bf(float x) {
  unsigned u = __builtin_bit_cast(unsigned, x);
  u += 0x7fffu + ((u >> 16) & 1u);
  return (unsigned short)(u >> 16);
}
__device__ __forceinline__ float bf2f(unsigned short s) {
  return __builtin_bit_cast(float, ((unsigned)s) << 16);
}

// ---------------------------------------------------------------------------
// K1: per-pixel MLP (118 -> 32 -> 32 -> 32 -> 32), writes h4 as bf16 [16384][32]
// x = [delta_enc(50) | scale_enc(50, constant) | kernel_enc(18, all -1)]
// constant parts folded into a precomputed bias bc[u].
// ---------------------------------------------------------------------------
__global__ __launch_bounds__(128) void k_mlp(
    const float* __restrict__ W1, const float* __restrict__ b1,
    const float* __restrict__ W2, const float* __restrict__ b2,
    const float* __restrict__ W3, const float* __restrict__ b3,
    const float* __restrict__ W4, const float* __restrict__ b4,
    unsigned short* __restrict__ h4out)
{
  __shared__ __align__(16) float W1s[118 * 32];
  __shared__ __align__(16) float W2s[1024], W3s[1024], W4s[1024];
  __shared__ __align__(16) float bcs[32], b2s[32], b3s[32], b4s[32];
  const int tid = threadIdx.x;
  for (int i = tid; i < 118 * 32; i += 128) W1s[i] = W1[i];
  for (int i = tid; i < 1024; i += 128) { W2s[i] = W2[i]; W3s[i] = W3[i]; W4s[i] = W4[i]; }
  if (tid < 32) { b2s[tid] = b2[tid]; b3s[tid] = b3[tid]; b4s[tid] = b4[tid]; }
  __syncthreads();
  if (tid < 32) {
    float a = b1[tid];
    for (int i = 0; i < 25; ++i) {
      float fi = 1.0f + (float)i * (1.0f / 24.0f);
      float xs = cosf(5.0f * PI_F * fi);                 // scale_enc (scale = 2.0 both dims)
      a += xs * (W1s[(50 + i) * 32 + tid] + W1s[(75 + i) * 32 + tid]);
    }
    for (int j = 100; j < 118; ++j) a -= W1s[j * 32 + tid];  // kernel_enc == -1
    bcs[tid] = a;
  }
  __syncthreads();

  const int pix = blockIdx.x * 128 + tid;   // 128 blocks x 128 threads = 16384
  const int h = pix >> 7, w = pix & 127;
  float acc[32];
  #pragma unroll
  for (int u = 0; u < 32; ++u) acc[u] = bcs[u];
  const float ga = PI_F * (2.0f * (float)h * (1.0f / 127.0f) + 1.0f);
  const float gb = PI_F * (2.0f * (float)w * (1.0f / 127.0f) + 1.0f);
  for (int i = 0; i < 25; ++i) {
    float fi = 1.0f + (float)i * (1.0f / 24.0f);
    float xa = cosf(ga * fi);
    float xb = cosf(gb * fi);
    #pragma unroll
    for (int u = 0; u < 32; ++u)
      acc[u] += xa * W1s[i * 32 + u] + xb * W1s[(25 + i) * 32 + u];
  }
  float hv[32];
  auto layer = [&](const float* Wl, const float* bl) {
    #pragma unroll
    for (int u = 0; u < 32; ++u) hv[u] = fmaxf(acc[u], 0.0f);
    #pragma unroll
    for (int u = 0; u < 32; ++u) acc[u] = bl[u];
    #pragma unroll
    for (int j = 0; j < 32; ++j) {
      float xj = hv[j];
      #pragma unroll
      for (int u = 0; u < 32; ++u) acc[u] += xj * Wl[j * 32 + u];
    }
  };
  layer(W2s, b2s);
  layer(W3s, b3s);
  layer(W4s, b4s);
  unsigned short o[32];
  #pragma unroll
  for (int u = 0; u < 32; ++u) o[u] = f2bf(fmaxf(acc[u], 0.0f));
  #pragma unroll
  for (int u = 0; u < 32; u += 8) {
    short8 v;
    #pragma unroll
    for (int e = 0; e < 8; ++e) v[e] = (short)o[u + e];
    *(short8*)&h4out[pix * 32 + u] = v;
  }
}

// ---------------------------------------------------------------------------
// K1b: transpose W_out -> WoutT[tc][j] bf16, W_proj -> WpT[f][c] bf16
// ---------------------------------------------------------------------------
__global__ __launch_bounds__(256) void k_prep(
    const float* __restrict__ Wout, const float* __restrict__ Wproj,
    unsigned short* __restrict__ WoutT, unsigned short* __restrict__ WpT)
{
  int idx = blockIdx.x * 256 + threadIdx.x;
  if (idx < 32 * 2304) {                     // WoutT[tc*32 + j] = Wout[j*2304 + tc]
    int tc = idx >> 5, j = idx & 31;
    WoutT[idx] = f2bf(Wout[j * 2304 + tc]);
  }
  int idx2 = idx - 73728;
  if (idx2 >= 0 && idx2 < 256 * 128) {       // WpT[f*256 + c] = Wproj[c*128 + f]
    int f = idx2 >> 8, c = idx2 & 255;
    WpT[idx2] = f2bf(Wproj[c * 128 + f]);
  }
}

// ---------------------------------------------------------------------------
// K2: fused ker-GEMM (MFMA) -> 3x3 tap-sum (VALU) -> projection GEMM (MFMA)
// Block = one output row h, 32 w-pixels, all 4 batches. C streamed in 8x32.
// ---------------------------------------------------------------------------
__global__ __launch_bounds__(256, 1) void k_main(
    const float* __restrict__ main_in,
    const float* __restrict__ b_out,
    const float* __restrict__ b_proj,
    const unsigned short* __restrict__ h4g,
    const unsigned short* __restrict__ WoutTg,
    const unsigned short* __restrict__ WpTg,
    float* __restrict__ out)
{
  __shared__ __align__(16) unsigned short WoutT_s[288][32];   // [t*32+cl][j]
  __shared__ __align__(16) unsigned short h4_s[32][32];       // [pix][j]
  __shared__ __align__(16) float xup_s[4][3][34][36];         // [b][dr][wcol][cl(32)+pad]
  __shared__ __align__(16) unsigned short ker_s[32][296];     // [pix][t*32+cl (288)+pad]
  __shared__ __align__(16) unsigned short p_s[128][32];       // [b*32+pix][cl]
  __shared__ __align__(16) unsigned short wpT_s[128][32];     // [f][cl]
  __shared__ __align__(16) float bout_s[288];                 // [t*32+cl]

  const int tid = threadIdx.x;
  const int lane = tid & 63;
  const int wv = tid >> 6;

  // XCD-friendly swizzle: 512 blocks, 64 contiguous tiles per XCD
  const int bx = blockIdx.x;
  const int sbx = (bx & 7) * 64 + (bx >> 3);
  const int h = sbx >> 2;
  const int w0 = (sbx & 3) * 32;

  // stage h4 tile once
  if (tid < 128) {
    int pix = tid >> 2, q = tid & 3;
    *(short8*)&h4_s[pix][q * 8] =
        *(const short8*)&h4g[(h * 128 + w0 + pix) * 32 + q * 8];
  }
  __syncthreads();

  // persistent A-fragment for GEMM-1 (this wave's 16-pixel half)
  const int mt1 = wv >> 1;            // 0..1
  const int ntb1 = (wv & 1) * 9;      // 0 or 9
  const short8 afrag = *(const short8*)&h4_s[mt1 * 16 + (lane & 15)][8 * (lane >> 4)];

  floatx4 acc2[2][8];
  #pragma unroll
  for (int i = 0; i < 2; ++i)
    #pragma unroll
    for (int n = 0; n < 8; ++n) acc2[i][n] = (floatx4){0.f, 0.f, 0.f, 0.f};

  const int tpix = tid >> 3;          // 0..31
  const int tclq = (tid & 7) * 4;     // 0,4,...,28

  for (int ch = 0; ch < 8; ++ch) {
    const int c0 = ch * 32;
    __syncthreads();   // protect p_s / wpT_s / xup_s readers of previous chunk

    // ---- staging ----
    #pragma unroll
    for (int it = 0; it < 5; ++it) {
      int u = tid + it * 256;
      if (u < 1152) {                  // 288 rows x 4 x 16B
        int row = u >> 2, jq = u & 3;
        int t = row >> 5, cl = row & 31;
        *(short8*)&WoutT_s[row][jq * 8] =
            *(const short8*)&WoutTg[(t * 256 + c0 + cl) * 32 + jq * 8];
      }
    }
    #pragma unroll
    for (int it = 0; it < 13; ++it) {
      int u = tid + it * 256;
      if (u < 3264) {                  // 4b x 3r x 34w x 8 float4
        int c4 = u & 7, s = u >> 3;
        int wcol = s % 34, s2 = s / 34;
        int row = s2 % 3, b = s2 / 3;
        int hr = h + row - 1, wc = w0 + wcol - 1;
        float4 v = make_float4(0.f, 0.f, 0.f, 0.f);
        if (hr >= 0 && hr < 128 && wc >= 0 && wc < 128)
          v = *(const float4*)&main_in[((b * 64 + (hr >> 1)) * 64 + (wc >> 1)) * 256 + c0 + c4 * 4];
        *(float4*)&xup_s[b][row][wcol][c4 * 4] = v;
      }
    }
    #pragma unroll
    for (int it = 0; it < 2; ++it) {
      int u = tid + it * 256;          // 512 = 128 f x 4 x 16B
      int f = u >> 2, q = u & 3;
      *(short8*)&wpT_s[f][q * 8] = *(const short8*)&WpTg[f * 256 + c0 + q * 8];
    }
    if (tid < 72) {
      int t = tid >> 3, c4 = tid & 7;
      *(float4*)&bout_s[t * 32 + c4 * 4] = *(const float4*)&b_out[t * 256 + c0 + c4 * 4];
    }
    __syncthreads();

    // ---- GEMM-1: ker[pix][tc] = h4 . WoutT + b_out ----
    #pragma unroll
    for (int q = 0; q < 9; ++q) {
      int nt = ntb1 + q;
      short8 bfrag = *(const short8*)&WoutT_s[nt * 16 + (lane & 15)][8 * (lane >> 4)];
      floatx4 d = {0.f, 0.f, 0.f, 0.f};
      d = __builtin_amdgcn_mfma_f32_16x16x32_bf16(afrag, bfrag, d, 0, 0, 0);
      int tc = nt * 16 + (lane & 15);
      float bo = bout_s[tc];
      int prow = mt1 * 16 + (lane >> 4) * 4;
      #pragma unroll
      for (int r = 0; r < 4; ++r)
        ker_s[prow + r][tc] = f2bf(d[r] + bo);
    }
    __syncthreads();

    // ---- tap-sum: p[b][pix][cl] = sum_t xup * ker ----
    {
      float pacc[4][4];
      #pragma unroll
      for (int b = 0; b < 4; ++b)
        #pragma unroll
        for (int qq = 0; qq < 4; ++qq) pacc[b][qq] = 0.f;
      #pragma unroll
      for (int t = 0; t < 9; ++t) {
        const int di = t / 3, dj = t % 3;
        ushort4 kv = *(const ushort4*)&ker_s[tpix][t * 32 + tclq];
        float k0 = bf2f(kv.x), k1 = bf2f(kv.y), k2 = bf2f(kv.z), k3 = bf2f(kv.w);
        #pragma unroll
        for (int b = 0; b < 4; ++b) {
          float4 xv = *(const float4*)&xup_s[b][di][tpix + dj][tclq];
          pacc[b][0] += k0 * xv.x; pacc[b][1] += k1 * xv.y;
          pacc[b][2] += k2 * xv.z; pacc[b][3] += k3 * xv.w;
        }
      }
      #pragma unroll
      for (int b = 0; b < 4; ++b) {
        ushort4 pv;
        pv.x = f2bf(pacc[b][0]); pv.y = f2bf(pacc[b][1]);
        pv.z = f2bf(pacc[b][2]); pv.w = f2bf(pacc[b][3]);
        *(ushort4*)&p_s[b * 32 + tpix][tclq] = pv;
      }
    }
    __syncthreads();

    // ---- GEMM-2: out[bp][f] += p . wpT ----
    {
      short8 pa0 = *(const short8*)&p_s[(wv * 2 + 0) * 16 + (lane & 15)][8 * (lane >> 4)];
      short8 pa1 = *(const short8*)&p_s[(wv * 2 + 1) * 16 + (lane & 15)][8 * (lane >> 4)];
      #pragma unroll
      for (int nt = 0; nt < 8; ++nt) {
        short8 wb = *(const short8*)&wpT_s[nt * 16 + (lane & 15)][8 * (lane >> 4)];
        acc2[0][nt] = __builtin_amdgcn_mfma_f32_16x16x32_bf16(pa0, wb, acc2[0][nt], 0, 0, 0);
        acc2[1][nt] = __builtin_amdgcn_mfma_f32_16x16x32_bf16(pa1, wb, acc2[1][nt], 0, 0, 0);
      }
    }
  }

  // ---- epilogue ----
  #pragma unroll
  for (int nt = 0; nt < 8; ++nt) {
    int f = nt * 16 + (lane & 15);
    float bpj = b_proj[f];
    #pragma unroll
    for (int im = 0; im < 2; ++im) {
      int bp0 = (wv * 2 + im) * 16 + (lane >> 4) * 4;
      #pragma unroll
      for (int r = 0; r < 4; ++r) {
        int bp = bp0 + r;
        int b = bp >> 5, pix = bp & 31;
        out[((b * 128 + h) * 128 + (w0 + pix)) * 128 + f] = acc2[im][nt][r] + bpj;
      }
    }
  }
}

// ---------------------------------------------------------------------------
extern "C" void kernel_launch(void* const* d_in, const int* in_sizes, int n_in,
                              void* d_out, int out_size, void* d_ws, size_t ws_size,
                              hipStream_t stream) {
  const float* main_in = (const float*)d_in[0];
  // d_in[1] = skip_connection: only defines H_t/W_t, unused numerically
  const float* W1 = (const float*)d_in[2];
  const float* b1 = (const float*)d_in[3];
  const float* W2 = (const float*)d_in[4];
  const float* b2 = (const float*)d_in[5];
  const float* W3 = (const float*)d_in[6];
  const float* b3 = (const float*)d_in[7];
  const float* W4 = (const float*)d_in[8];
  const float* b4 = (const float*)d_in[9];
  const float* Wout = (const float*)d_in[10];
  const float* bout = (const float*)d_in[11];
  const float* Wproj = (const float*)d_in[12];
  const float* bproj = (const float*)d_in[13];
  float* outp = (float*)d_out;

  // workspace layout (bf16): h4 [16384*32] | WoutT [2304*32] | WpT [128*256]
  unsigned short* h4ws = (unsigned short*)d_ws;                       // 1,048,576 B
  unsigned short* WoutT = (unsigned short*)((char*)d_ws + 1048576);   //   147,456 B
  unsigned short* WpT = (unsigned short*)((char*)d_ws + 1048576 + 147456); // 65,536 B

  k_mlp<<<dim3(128), dim3(128), 0, stream>>>(W1, b1, W2, b2, W3, b3, W4, b4, h4ws);
  k_prep<<<dim3(416), dim3(256), 0, stream>>>(Wout, Wproj, WoutT, WpT);
  k_main<<<dim3(512), dim3(256), 0, stream>>>(main_in, bout, bproj, h4ws, WoutT, WpT, outp);
}